// Round 10
// baseline (134.541 us; speedup 1.0000x reference)
//
#include <hip/hip_runtime.h>
#include <stdint.h>

// ---------------------------------------------------------------------------
// PlaneEmbeddingNetwork, round 15 (resubmit; R9's container failed -- infra).
// R14: 45.8us; WRITE fixed at 62.5MB; VALU 56% / MFMA 21% / HBM 47% / occ 60%
// -- latency-bound mix, nothing saturated. Diagnosis:
//  (a) VGPR=32 tell: (256,8) bound forced weight-fragment reloads + serialized
//      the 4 unrolled iterations (~1000 VALU/wave vs ~600 in source).
//  (b) gather fetches 64B/token but consumes 32B (f16); node table is 16MB
//      (L2/L3-resident, ~8x reuse/node) yet ~97MB of gather FETCH.
// R15: 1) f16 node table in ws (8MB, pre-pass w/ identical v_cvt_pkrtz;
//         f32 fallback if ws too small): halves gather bytes, better L2.
//      2) __launch_bounds__(256,6): VGPR cap 85 -> weights stay resident.
//      3) stage-major PAIR interleave: 2 independent MFMA chains per wave.
// Predict: FETCH ~55-70MB, dur ~33-38us, MfmaUtil ~26%, VGPR 60-80 (no
// scratch), WRITE 62.5MB, absmax exactly 0.00390625.
// ---------------------------------------------------------------------------

typedef _Float16 v2h __attribute__((ext_vector_type(2)));
typedef __fp16 h4 __attribute__((ext_vector_type(4)));   // MFMA A/B frag
typedef float f32x4 __attribute__((ext_vector_type(4)));
typedef uint32_t u32x2 __attribute__((ext_vector_type(2)));

#define DPP_ROT1 0x39  // lane t <- (t+1)&3 within quad
#define DPP_ROT2 0x4E  // lane t <- (t+2)&3
#define DPP_ROT3 0x93  // lane t <- (t+3)&3

template<int CTRL>
static __device__ __forceinline__ float dppf(float x) {
    return __builtin_bit_cast(float,
        __builtin_amdgcn_mov_dpp(__builtin_bit_cast(int, x), CTRL, 0xF, 0xF, true));
}

static __device__ __forceinline__ v2h pkh(float a, float b) {
    v2h r; r.x = (_Float16)a; r.y = (_Float16)b; return r;  // RNE (setup only)
}
static __device__ __forceinline__ v2h pkrtz(float a, float b) {
#if __has_builtin(__builtin_amdgcn_cvt_pkrtz)
    return __builtin_bit_cast(v2h, __builtin_amdgcn_cvt_pkrtz(a, b));
#else
    return pkh(a, b);
#endif
}
static __device__ __forceinline__ uint32_t bcu(v2h h) {
    return __builtin_bit_cast(uint32_t, h);
}
static __device__ __forceinline__ h4 mkh4(uint32_t lo, uint32_t hi) {
    u32x2 t; t.x = lo; t.y = hi; return __builtin_bit_cast(h4, t);
}
static __device__ __forceinline__ h4 ld2h(const uint32_t* p) {
    u32x2 t; t.x = p[0]; t.y = p[1]; return __builtin_bit_cast(h4, t);
}
static __device__ __forceinline__ f32x4 mfma16(h4 a, h4 b, f32x4 c) {
    return __builtin_amdgcn_mfma_f32_16x16x16f16(a, b, c, 0, 0, 0);
}
static __device__ __forceinline__ h4 packC(f32x4 c) {
    return mkh4(bcu(pkrtz(c[0], c[1])), bcu(pkrtz(c[2], c[3])));
}
static __device__ __forceinline__ h4 packCrelu(f32x4 c) {
    return mkh4(bcu(pkrtz(fmaxf(c[0], 0.f), fmaxf(c[1], 0.f))),
                bcu(pkrtz(fmaxf(c[2], 0.f), fmaxf(c[3], 0.f))));
}
static __device__ __forceinline__ h4 selh(bool keep, h4 x) {
    u32x2 t = __builtin_bit_cast(u32x2, x);
    u32x2 r; r.x = keep ? t.x : 0u; r.y = keep ? t.y : 0u;
    return __builtin_bit_cast(h4, r);
}

// ---------------------------------------------------------------------------
// fold_w: byte-identical to R11..R14.
// ws dwords: [0..384) Eqkv | [384..640) Eh | [640..672) b1 f32 |
//            [672..1184) Efco | [2048..2048+nodes*8) f16 node table
// ---------------------------------------------------------------------------
__global__ void fold_w(const float* __restrict__ w_in,
                       const float* __restrict__ w_out,
                       const float* __restrict__ b_out,
                       const float* __restrict__ fc_w,
                       const float* __restrict__ fc_b,
                       const float* __restrict__ fco_w,
                       uint32_t* __restrict__ wsu) {
    const int tid = threadIdx.x;
    if (blockIdx.x == 0) {
        if (tid < 384) {                   // Eqkv
            const int T = tid >> 7, r = tid & 127, l = r >> 1, d = r & 1;
            const int o = 16 * T + (l & 15), k0 = 4 * (l >> 4) + 2 * d;
            wsu[tid] = bcu(pkh(w_in[k0 * 48 + o], w_in[(k0 + 1) * 48 + o]));
        } else if (tid < 640) {            // Eh
            const int i = tid - 384, b = i >> 7, r = i & 127, l = r >> 1, d = r & 1;
            const int c = 16 * b + (l & 15), k0 = 4 * (l >> 4) + 2 * d;
            float a0 = 0.f, a1 = 0.f;
#pragma unroll
            for (int e = 0; e < 16; ++e) {
                a0 = fmaf(w_out[k0 * 16 + e],       fc_w[e * 32 + c], a0);
                a1 = fmaf(w_out[(k0 + 1) * 16 + e], fc_w[e * 32 + c], a1);
            }
            wsu[tid] = bcu(pkh(a0, a1));
        }
    } else {
        if (tid < 32) {                    // b1 (f32)
            float acc = fc_b[tid];
#pragma unroll
            for (int e = 0; e < 16; ++e)
                acc = fmaf(b_out[e], fc_w[e * 32 + tid], acc);
            reinterpret_cast<float*>(wsu)[640 + tid] = acc;
        } else if (tid < 544) {            // Efco (0.25 pooling folded in)
            const int i = tid - 32;
            const int kt = i >> 8, n = (i >> 7) & 1, r = i & 127, l = r >> 1, d = r & 1;
            const int col = 16 * n + (l & 15), k0 = 16 * kt + 4 * (l >> 4) + 2 * d;
            wsu[672 + i] = bcu(pkh(fco_w[k0 * 32 + col] * 0.25f,
                                   fco_w[(k0 + 1) * 32 + col] * 0.25f));
        }
    }
}

// node f32 -> packed f16 table (identical pkrtz rounding to the in-kernel path)
__global__ void cvt_node(const float* __restrict__ node,
                         uint32_t* __restrict__ nt, int ndw) {
    const int i = blockIdx.x * 256 + threadIdx.x;
    if (i < ndw) nt[i] = bcu(pkrtz(node[2 * i], node[2 * i + 1]));
}

template<bool F16>
__launch_bounds__(256, 6)
__global__ void face_net(const float* __restrict__ node,
                         const uint32_t* __restrict__ nt,
                         const int*   __restrict__ fids,
                         const float* __restrict__ b_in,
                         const uint32_t* __restrict__ wsu,
                         const float* __restrict__ fco_b,
                         float* __restrict__ out, int F) {
    const int l   = threadIdx.x & 63;
    const int wid = threadIdx.x >> 6;
    const int token_base = blockIdx.x * 256 + wid * 64;   // wave = 64 tokens
    const int total = 4 * F;
    if (token_base >= total) return;
    const int c0 = l & 15, g2 = l >> 4;

    // ---- gathers up front: lane holds token 16a+c0, comps 4g2..4g2+3.
    h4 X[4];
#pragma unroll
    for (int a = 0; a < 4; ++a) {
        int tok = token_base + 16 * a + c0;
        tok = tok < total ? tok : total - 1;
        const int nid = fids[tok];
        if constexpr (F16) {
            const u32x2 xw = *reinterpret_cast<const u32x2*>(
                nt + (size_t)nid * 8 + g2 * 2);
            X[a] = __builtin_bit_cast(h4, xw);
        } else {
            const float4 xv = *reinterpret_cast<const float4*>(
                node + (size_t)nid * 16 + g2 * 4);
            X[a] = mkh4(bcu(pkrtz(xv.x, xv.y)), bcu(pkrtz(xv.z, xv.w)));
        }
    }

    // ---- weight fragments (resident in VGPR under the (256,6) budget)
    const h4 WqT  = ld2h(wsu + 0   + l * 2);   // A-frag of Wq^T
    const h4 WkT  = ld2h(wsu + 128 + l * 2);   // A-frag of Wk^T
    const h4 WvB  = ld2h(wsu + 256 + l * 2);   // B-frag of Wv
    const h4 EhA0 = ld2h(wsu + 384 + l * 2);   // A-frag of W1^T, hid 0..15
    const h4 EhA1 = ld2h(wsu + 512 + l * 2);   // A-frag of W1^T, hid 16..31
    const h4 Ef00 = ld2h(wsu + 672 + 0 * 128 + l * 2);  // B-frag 0.25Wfco k0,n0
    const h4 Ef01 = ld2h(wsu + 672 + 1 * 128 + l * 2);  // k0,n1
    const h4 Ef10 = ld2h(wsu + 672 + 2 * 128 + l * 2);  // k1,n0
    const h4 Ef11 = ld2h(wsu + 672 + 3 * 128 + l * 2);  // k1,n1

    // ---- biases
    const float4 bq4 = *reinterpret_cast<const float4*>(b_in + 4 * g2);
    const float  bv  = b_in[32 + c0];
    const float* b1f = reinterpret_cast<const float*>(wsu) + 640;
    const float4 b10 = *reinterpret_cast<const float4*>(b1f + 4 * g2);
    const float4 b11 = *reinterpret_cast<const float4*>(b1f + 16 + 4 * g2);
    const float fb0s = fco_b[c0];
    const float fb1s = fco_b[16 + c0];

    const bool scoreH0 = (g2 < 2);
    const bool pvH0    = (c0 < 8);
    const bool valid   = (g2 == (c0 >> 2));
    const int fbase = token_base >> 2;
    const float C = 0.51006974841f;         // (1/sqrt(8)) * log2(e)
    const f32x4 zz = {0.f, 0.f, 0.f, 0.f};
    const f32x4 cq = {bq4.x, bq4.y, bq4.z, bq4.w};
    const f32x4 cv = {bv, bv, bv, bv};
    const f32x4 ch0 = {b10.x, b10.y, b10.z, b10.w};
    const f32x4 ch1 = {b11.x, b11.y, b11.z, b11.w};

    // ---- 2 passes x 2 interleaved iterations (stage-major in the pair):
    //      each stage issues both chains' MFMAs back-to-back -> 2x in-wave ILP.
#pragma unroll
    for (int ap = 0; ap < 2; ++ap) {
        // stage 1: projections (6 independent MFMAs)
        f32x4 Dq[2], Dk[2], Dv[2];
#pragma unroll
        for (int j = 0; j < 2; ++j) {
            const h4 x = X[2 * ap + j];
            Dq[j] = mfma16(WqT, x, cq);   // Q^T[qcomp][token]
            Dk[j] = mfma16(WkT, x, zz);   // K^T[kcomp][token]
            Dv[j] = mfma16(x, WvB, cv);   // V[token][vcomp]
        }
        // stage 2: packs
        h4 qB[2], kA[2], vA[2];
#pragma unroll
        for (int j = 0; j < 2; ++j) {
            qB[j] = packC(Dq[j]); kA[j] = packC(Dk[j]); vA[j] = packC(Dv[j]);
        }
        // stage 3: scores (4 independent MFMAs)
        f32x4 S0[2], S1[2];
#pragma unroll
        for (int j = 0; j < 2; ++j) {
            S0[j] = mfma16(selh(scoreH0,  kA[j]), qB[j], zz);
            S1[j] = mfma16(selh(!scoreH0, kA[j]), qB[j], zz);
        }
        // stage 4: in-lane softmax (valid lanes: g2==c0>>2) + PB packs
        h4 PB0[2], PB1[2];
#pragma unroll
        for (int j = 0; j < 2; ++j) {
            const float e00 = __builtin_amdgcn_exp2f(S0[j][0] * C);
            const float e01 = __builtin_amdgcn_exp2f(S0[j][1] * C);
            const float e02 = __builtin_amdgcn_exp2f(S0[j][2] * C);
            const float e03 = __builtin_amdgcn_exp2f(S0[j][3] * C);
            const float e10 = __builtin_amdgcn_exp2f(S1[j][0] * C);
            const float e11 = __builtin_amdgcn_exp2f(S1[j][1] * C);
            const float e12 = __builtin_amdgcn_exp2f(S1[j][2] * C);
            const float e13 = __builtin_amdgcn_exp2f(S1[j][3] * C);
            const float r0 = __builtin_amdgcn_rcpf((e00 + e01) + (e02 + e03));
            const float r1 = __builtin_amdgcn_rcpf((e10 + e11) + (e12 + e13));
            PB0[j] = selh(valid, mkh4(bcu(pkrtz(e00 * r0, e01 * r0)),
                                      bcu(pkrtz(e02 * r0, e03 * r0))));
            PB1[j] = selh(valid, mkh4(bcu(pkrtz(e10 * r1, e11 * r1)),
                                      bcu(pkrtz(e12 * r1, e13 * r1))));
        }
        // stage 5: PV (2 chains of depth 2)
        f32x4 Ot[2];
#pragma unroll
        for (int j = 0; j < 2; ++j) {
            Ot[j] = mfma16(selh(pvH0,  vA[j]), PB0[j], zz);
            Ot[j] = mfma16(selh(!pvH0, vA[j]), PB1[j], Ot[j]);
        }
        // stage 6: h (pack + 4 MFMAs)
        h4 hB[2];
#pragma unroll
        for (int j = 0; j < 2; ++j) hB[j] = packC(Ot[j]);
        f32x4 H0[2], H1[2];
#pragma unroll
        for (int j = 0; j < 2; ++j) {
            H0[j] = mfma16(EhA0, hB[j], ch0);
            H1[j] = mfma16(EhA1, hB[j], ch1);
        }
        // stage 7: relu packs + fco (8 MFMAs, 2 chains of depth 2 each)
        f32x4 O0[2], O1[2];
#pragma unroll
        for (int j = 0; j < 2; ++j) {
            const h4 AH0 = packCrelu(H0[j]);
            const h4 AH1 = packCrelu(H1[j]);
            O0[j] = mfma16(AH1, Ef10, mfma16(AH0, Ef00, zz));
            O1[j] = mfma16(AH1, Ef11, mfma16(AH0, Ef01, zz));
        }
        // stage 8: pool (3 in-lane adds) + quad-transpose store
#pragma unroll
        for (int j = 0; j < 2; ++j) {
            const int a = 2 * ap + j;
            const float o0 = ((O0[j][0] + O0[j][1]) + (O0[j][2] + O0[j][3])) + fb0s;
            const float o1 = ((O1[j][0] + O1[j][1]) + (O1[j][2] + O1[j][3])) + fb1s;
            const float a1 = dppf<DPP_ROT1>(o0);
            const float a2 = dppf<DPP_ROT2>(o0);
            const float a3 = dppf<DPP_ROT3>(o0);
            const float b1 = dppf<DPP_ROT1>(o1);
            const float b2 = dppf<DPP_ROT2>(o1);
            const float b3 = dppf<DPP_ROT3>(o1);
            const int face = fbase + 4 * a + g2;
            if ((c0 & 2) == 0 && face < F) {
                const bool t0 = (c0 & 1) == 0;
                const int q = c0 >> 2;
                const float4 st = make_float4(t0 ? o0 : b3,
                                              t0 ? a1 : o1,
                                              t0 ? a2 : b1,
                                              t0 ? a3 : b2);
                float* ob = out + (size_t)face * 32 + (t0 ? 4 * q : 16 + 4 * q);
                *reinterpret_cast<float4*>(ob) = st;
            }
        }
    }
}

extern "C" void kernel_launch(void* const* d_in, const int* in_sizes, int n_in,
                              void* d_out, int out_size, void* d_ws, size_t ws_size,
                              hipStream_t stream) {
    const float* node  = (const float*)d_in[0];
    const int*   fids  = (const int*)  d_in[1];
    const float* w_in  = (const float*)d_in[2];
    const float* b_in  = (const float*)d_in[3];
    const float* w_out = (const float*)d_in[4];
    const float* b_out = (const float*)d_in[5];
    const float* fc_w  = (const float*)d_in[6];
    const float* fc_b  = (const float*)d_in[7];
    const float* fco_w = (const float*)d_in[8];
    const float* fco_b = (const float*)d_in[9];
    float* out = (float*)d_out;
    uint32_t* wsu = (uint32_t*)d_ws;
    const int F = in_sizes[1] / 4;
    const int ndw = in_sizes[0] / 2;            // node dwords in f16 table
    const size_t need = (2048 + (size_t)ndw) * 4;
    const bool f16tab = ws_size >= need;

    hipLaunchKernelGGL(fold_w, dim3(2), dim3(640), 0, stream,
                       w_in, w_out, b_out, fc_w, fc_b, fco_w, wsu);
    if (f16tab) {
        hipLaunchKernelGGL(cvt_node, dim3((ndw + 255) / 256), dim3(256), 0,
                           stream, node, wsu + 2048, ndw);
    }
    const int threads = F * 4;
    const int blocks = (threads + 255) / 256;
    if (f16tab) {
        hipLaunchKernelGGL((face_net<true>), dim3(blocks), dim3(256), 0, stream,
                           node, wsu + 2048, fids, b_in, wsu, fco_b, out, F);
    } else {
        hipLaunchKernelGGL((face_net<false>), dim3(blocks), dim3(256), 0, stream,
                           node, wsu, fids, b_in, wsu, fco_b, out, F);
    }
}